// Round 1
// baseline (171.688 us; speedup 1.0000x reference)
//
#include <hip/hip_runtime.h>

// CurvatureLoss: pred (8,4,1024,1024) fp32 -> scalar loss.
// target input is unused by the reference; we never read it.

namespace {
constexpr int H = 1024, W = 1024, B = 8;
constexpr int TILE = 32;
constexpr int PT = TILE + 6;  // prob tile with halo 3 -> 38
constexpr int LT = TILE + 4;  // lap tile with halo 2  -> 36
constexpr int GT = TILE + 2;  // grad tile with halo 1 -> 34
constexpr int NTHREADS = 256;
}

// ws layout: float s[24] | unsigned c[24]  (24 = 8 batches x 3 fields)
__global__ void zero_ws_kernel(unsigned int* ws) {
    if (threadIdx.x < 48) ws[threadIdx.x] = 0u;
}

__global__ __launch_bounds__(NTHREADS)
void curvature_main(const float* __restrict__ pred,
                    float* __restrict__ s_ws,
                    unsigned int* __restrict__ c_ws) {
    __shared__ float sP[3][PT * PT];   // 3 prob fields, halo 3
    __shared__ float sL[LT * LT];      // laplacian, halo 2 (reused per field)
    __shared__ float sGx[GT * GT];     // gx, halo 1
    __shared__ float sGy[GT * GT];     // gy, halo 1
    __shared__ float redS[3][NTHREADS / 64];
    __shared__ unsigned int redC[3][NTHREADS / 64];

    const int b = blockIdx.z;
    const int oh = blockIdx.y * TILE;
    const int ow = blockIdx.x * TILE;
    const int tid = threadIdx.x;
    const float* base = pred + (size_t)b * 4 * H * W;

    // Stage 0: softmax over the 4 channels; store p1, p1+p2, p3 with halo 3.
    // Out-of-image positions store 0 (matches jnp zero-padding of shifts).
    for (int i = tid; i < PT * PT; i += NTHREADS) {
        const int ph = i / PT, pw = i % PT;
        const int gh = oh - 3 + ph, gw = ow - 3 + pw;
        float p1 = 0.f, p12 = 0.f, p3 = 0.f;
        if ((unsigned)gh < (unsigned)H && (unsigned)gw < (unsigned)W) {
            const size_t off = (size_t)gh * W + gw;
            const float x0 = base[off];
            const float x1 = base[off + (size_t)H * W];
            const float x2 = base[off + 2 * (size_t)H * W];
            const float x3 = base[off + 3 * (size_t)H * W];
            const float m = fmaxf(fmaxf(x0, x1), fmaxf(x2, x3));
            const float e0 = __expf(x0 - m), e1 = __expf(x1 - m);
            const float e2 = __expf(x2 - m), e3 = __expf(x3 - m);
            const float inv = 1.0f / (e0 + e1 + e2 + e3);
            p1 = e1 * inv; p12 = (e1 + e2) * inv; p3 = e3 * inv;
        }
        sP[0][i] = p1; sP[1][i] = p12; sP[2][i] = p3;
    }

    float s_acc[3];
    unsigned int c_acc[3];

    for (int f = 0; f < 3; ++f) {
        __syncthreads();  // prob ready (f=0) / previous field's G reads done (f>0)
        const float* __restrict__ P = sP[f];
        // Stage 1: lap with halo 2. Mask out-of-image to 0.
        for (int i = tid; i < LT * LT; i += NTHREADS) {
            const int lh = i / LT, lw = i % LT;
            const int ph = lh + 1, pw = lw + 1;       // coords in sP
            const int gh = oh - 2 + lh, gw = ow - 2 + lw;
            float v = 0.f;
            if ((unsigned)gh < (unsigned)H && (unsigned)gw < (unsigned)W) {
                v = P[(ph - 1) * PT + pw] + P[(ph + 1) * PT + pw]
                  + P[ph * PT + pw - 1] + P[ph * PT + pw + 1]
                  - 4.0f * P[ph * PT + pw];
            }
            sL[i] = v;
        }
        __syncthreads();
        // Stage 2: gx, gy with halo 1. Mask out-of-image to 0.
        for (int i = tid; i < GT * GT; i += NTHREADS) {
            const int lh = i / GT, lw = i % GT;
            const int Lh = lh + 1, Lw = lw + 1;       // coords in sL
            const int gh = oh - 1 + lh, gw = ow - 1 + lw;
            float gx = 0.f, gy = 0.f;
            if ((unsigned)gh < (unsigned)H && (unsigned)gw < (unsigned)W) {
                gx = sL[Lh * LT + Lw + 1] - sL[Lh * LT + Lw - 1];
                gy = sL[(Lh + 1) * LT + Lw] - sL[(Lh - 1) * LT + Lw];
            }
            sGx[i] = gx; sGy[i] = gy;
        }
        __syncthreads();
        // Stage 3: curvature per output pixel; accumulate sum & nonzero count.
        float s = 0.f; unsigned int cnt = 0;
        for (int i = tid; i < TILE * TILE; i += NTHREADS) {
            const int lh = i / TILE, lw = i % TILE;
            const int Gh = lh + 1, Gw = lw + 1;       // coords in sGx/sGy
            const float gx  = sGx[Gh * GT + Gw];
            const float gy  = sGy[Gh * GT + Gw];
            const float gxp = sGx[Gh * GT + Gw + 1];
            const float gxm = sGx[Gh * GT + Gw - 1];
            const float gyp = sGy[(Gh + 1) * GT + Gw];
            const float gym = sGy[(Gh - 1) * GT + Gw];
            const float hxx = 2.f * gx - gxp - gxm;
            const float hxy = gxp - gxm;
            const float hyy = 2.f * gy - gyp - gym;
            const float oy = 1.f + gy, ox = 1.f + gx;
            const float numer = hxx * oy * oy - 2.f * hxy * gx * gy + hyy * ox * ox;
            const float x = 1.f + gx * gx + gy * gy;
            const float den = 2.f * x * sqrtf(x);
            const float curv = numer / den;
            const float negc = fmaxf(-curv, 0.f);
            s += negc;
            cnt += (negc != 0.f) ? 1u : 0u;
        }
        s_acc[f] = s; c_acc[f] = cnt;
    }

    // Block reduction: wave shuffle then cross-wave via LDS, then atomics.
    const int lane = tid & 63;
    const int wid = tid >> 6;
    for (int f = 0; f < 3; ++f) {
        float v = s_acc[f];
        unsigned int c = c_acc[f];
        for (int off = 32; off > 0; off >>= 1) {
            v += __shfl_down(v, off, 64);
            c += __shfl_down(c, off, 64);
        }
        if (lane == 0) { redS[f][wid] = v; redC[f][wid] = c; }
    }
    __syncthreads();
    if (tid < 3) {
        float v = 0.f; unsigned int c = 0;
        for (int w2 = 0; w2 < NTHREADS / 64; ++w2) {
            v += redS[tid][w2];
            c += redC[tid][w2];
        }
        atomicAdd(&s_ws[b * 3 + tid], v);
        atomicAdd(&c_ws[b * 3 + tid], c);
    }
}

__global__ void finalize_kernel(const float* __restrict__ s_ws,
                                const unsigned int* __restrict__ c_ws,
                                float* __restrict__ out) {
    const int lane = threadIdx.x;
    float v = 0.f;
    if (lane < 24) {
        const float s = s_ws[lane];
        const unsigned int c = c_ws[lane];
        v = (c > 0) ? s / (float)c : 0.f;  // max(c,1)==c when c>0
    }
    for (int off = 32; off > 0; off >>= 1) v += __shfl_down(v, off, 64);
    if (lane == 0) out[0] = v;
}

extern "C" void kernel_launch(void* const* d_in, const int* in_sizes, int n_in,
                              void* d_out, int out_size, void* d_ws, size_t ws_size,
                              hipStream_t stream) {
    const float* pred = (const float*)d_in[0];
    float* s_ws = (float*)d_ws;
    unsigned int* c_ws = (unsigned int*)((char*)d_ws + 24 * sizeof(float));
    float* out = (float*)d_out;

    hipLaunchKernelGGL(zero_ws_kernel, dim3(1), dim3(64), 0, stream,
                       (unsigned int*)d_ws);
    dim3 grid(W / TILE, H / TILE, B);
    hipLaunchKernelGGL(curvature_main, grid, dim3(NTHREADS), 0, stream,
                       pred, s_ws, c_ws);
    hipLaunchKernelGGL(finalize_kernel, dim3(1), dim3(64), 0, stream,
                       s_ws, c_ws, out);
}

// Round 2
// 154.423 us; speedup vs baseline: 1.1118x; 1.1118x over previous
//
#include <hip/hip_runtime.h>

// CurvatureLoss: pred (8,4,1024,1024) fp32 -> scalar loss.
// target input is unused by the reference; we never read it.

namespace {
constexpr int H = 1024, W = 1024, B = 8;
constexpr int TILE = 32;
constexpr int PT = TILE + 6;  // prob tile with halo 3 -> 38
constexpr int LT = TILE + 4;  // lap tile with halo 2  -> 36
constexpr int NTHREADS = 256;
constexpr int NWAVES = NTHREADS / 64;
}

// ws layout: float s[24] | unsigned c[24]  (24 = 8 batches x 3 fields)
__global__ void zero_ws_kernel(unsigned int* ws) {
    if (threadIdx.x < 48) ws[threadIdx.x] = 0u;
}

template <bool INTERIOR>
__device__ __forceinline__ void curvature_body(
    const float* __restrict__ base, int b, int oh, int ow, int tid,
    float (&sP)[3][PT * PT], float (&sL)[LT * LT],
    float (&redS)[3][NWAVES], unsigned int (&redC)[3][NWAVES],
    float* __restrict__ s_ws, unsigned int* __restrict__ c_ws) {

    // Stage 0: softmax over 4 channels; store p1, p1+p2, p3 with halo 3.
    for (int i = tid; i < PT * PT; i += NTHREADS) {
        const int ph = i / PT, pw = i - ph * PT;
        const int gh = oh - 3 + ph, gw = ow - 3 + pw;
        float p1 = 0.f, p12 = 0.f, p3 = 0.f;
        if (INTERIOR || ((unsigned)gh < (unsigned)H && (unsigned)gw < (unsigned)W)) {
            const size_t off = (size_t)gh * W + gw;
            const float x0 = base[off];
            const float x1 = base[off + (size_t)H * W];
            const float x2 = base[off + 2 * (size_t)H * W];
            const float x3 = base[off + 3 * (size_t)H * W];
            const float m = fmaxf(fmaxf(x0, x1), fmaxf(x2, x3));
            const float e0 = __expf(x0 - m), e1 = __expf(x1 - m);
            const float e2 = __expf(x2 - m), e3 = __expf(x3 - m);
            const float inv = __builtin_amdgcn_rcpf(e0 + e1 + e2 + e3);
            p1 = e1 * inv; p12 = (e1 + e2) * inv; p3 = e3 * inv;
        }
        sP[0][i] = p1; sP[1][i] = p12; sP[2][i] = p3;
    }

    float s_acc[3];
    unsigned int c_acc[3];

    for (int f = 0; f < 3; ++f) {
        __syncthreads();  // prob ready (f=0) / previous field's sL reads done
        const float* __restrict__ P = sP[f];
        // Stage 1: lap with halo 2. Out-of-image -> 0.
        for (int i = tid; i < LT * LT; i += NTHREADS) {
            const int lh = i / LT, lw = i - lh * LT;
            const int ph = lh + 1, pw = lw + 1;  // coords in sP
            float v = 0.f;
            if (INTERIOR || ((unsigned)(oh - 2 + lh) < (unsigned)H &&
                             (unsigned)(ow - 2 + lw) < (unsigned)W)) {
                v = P[(ph - 1) * PT + pw] + P[(ph + 1) * PT + pw]
                  + P[ph * PT + pw - 1] + P[ph * PT + pw + 1]
                  - 4.0f * P[ph * PT + pw];
            }
            sL[i] = v;
        }
        __syncthreads();
        // Stage 2+3 fused: compute gx/gy on the fly from sL, then curvature.
        float s = 0.f;
        unsigned int cnt = 0;
        for (int i = tid; i < TILE * TILE; i += NTHREADS) {
            const int lh = i >> 5, lw = i & 31;
            const int Lh = lh + 2, Lw = lw + 2;  // coords in sL
            // Center row (5 cols) + center col (4 rows) of lap values.
            const float cm2 = sL[Lh * LT + Lw - 2];
            const float cm1 = sL[Lh * LT + Lw - 1];
            const float c0  = sL[Lh * LT + Lw];
            const float cp1 = sL[Lh * LT + Lw + 1];
            const float cp2 = sL[Lh * LT + Lw + 2];
            const float rm2 = sL[(Lh - 2) * LT + Lw];
            const float rm1 = sL[(Lh - 1) * LT + Lw];
            const float rp1 = sL[(Lh + 1) * LT + Lw];
            const float rp2 = sL[(Lh + 2) * LT + Lw];
            const float gx = cp1 - cm1;       // gx(0,0)
            const float gy = rp1 - rm1;       // gy(0,0)
            float gxp = cp2 - c0;             // gx(0,+1)
            float gxm = c0 - cm2;             // gx(0,-1)
            float gyp = rp2 - c0;             // gy(+1,0)
            float gym = c0 - rm2;             // gy(-1,0)
            if (!INTERIOR) {
                const int gh = oh + lh, gw = ow + lw;
                if (gw + 1 >= W) gxp = 0.f;
                if (gw - 1 < 0)  gxm = 0.f;
                if (gh + 1 >= H) gyp = 0.f;
                if (gh - 1 < 0)  gym = 0.f;
            }
            const float hxx = 2.f * gx - gxp - gxm;
            const float hxy = gxp - gxm;
            const float hyy = 2.f * gy - gyp - gym;
            const float oy = 1.f + gy, ox = 1.f + gx;
            const float numer = hxx * oy * oy - 2.f * hxy * gx * gy + hyy * ox * ox;
            const float x = 1.f + gx * gx + gy * gy;
            const float rs = __builtin_amdgcn_rsqf(x);  // x^-0.5
            const float inv_den = 0.5f * rs * rs * rs;  // 1/(2 x^1.5)
            const float curv = numer * inv_den;
            const float negc = fmaxf(-curv, 0.f);
            s += negc;
            cnt += (negc != 0.f) ? 1u : 0u;
        }
        s_acc[f] = s; c_acc[f] = cnt;
    }

    // Block reduction: wave shuffle, cross-wave via LDS, then atomics.
    const int lane = tid & 63;
    const int wid = tid >> 6;
    for (int f = 0; f < 3; ++f) {
        float v = s_acc[f];
        unsigned int c = c_acc[f];
        for (int off = 32; off > 0; off >>= 1) {
            v += __shfl_down(v, off, 64);
            c += __shfl_down(c, off, 64);
        }
        if (lane == 0) { redS[f][wid] = v; redC[f][wid] = c; }
    }
    __syncthreads();
    if (tid < 3) {
        float v = 0.f;
        unsigned int c = 0;
        for (int w2 = 0; w2 < NWAVES; ++w2) { v += redS[tid][w2]; c += redC[tid][w2]; }
        atomicAdd(&s_ws[b * 3 + tid], v);
        atomicAdd(&c_ws[b * 3 + tid], c);
    }
}

__global__ __launch_bounds__(NTHREADS)
void curvature_main(const float* __restrict__ pred,
                    float* __restrict__ s_ws,
                    unsigned int* __restrict__ c_ws) {
    __shared__ float sP[3][PT * PT];
    __shared__ float sL[LT * LT];
    __shared__ float redS[3][NWAVES];
    __shared__ unsigned int redC[3][NWAVES];

    const int b = blockIdx.z;
    const int oh = blockIdx.y * TILE;
    const int ow = blockIdx.x * TILE;
    const int tid = threadIdx.x;
    const float* base = pred + (size_t)b * 4 * H * W;

    const bool interior = (oh >= 3) && (oh + TILE + 3 <= H) &&
                          (ow >= 3) && (ow + TILE + 3 <= W);
    if (interior) {
        curvature_body<true>(base, b, oh, ow, tid, sP, sL, redS, redC, s_ws, c_ws);
    } else {
        curvature_body<false>(base, b, oh, ow, tid, sP, sL, redS, redC, s_ws, c_ws);
    }
}

__global__ void finalize_kernel(const float* __restrict__ s_ws,
                                const unsigned int* __restrict__ c_ws,
                                float* __restrict__ out) {
    const int lane = threadIdx.x;
    float v = 0.f;
    if (lane < 24) {
        const float s = s_ws[lane];
        const unsigned int c = c_ws[lane];
        v = (c > 0) ? s / (float)c : 0.f;  // max(c,1)==c when c>0
    }
    for (int off = 32; off > 0; off >>= 1) v += __shfl_down(v, off, 64);
    if (lane == 0) out[0] = v;
}

extern "C" void kernel_launch(void* const* d_in, const int* in_sizes, int n_in,
                              void* d_out, int out_size, void* d_ws, size_t ws_size,
                              hipStream_t stream) {
    const float* pred = (const float*)d_in[0];
    float* s_ws = (float*)d_ws;
    unsigned int* c_ws = (unsigned int*)((char*)d_ws + 24 * sizeof(float));
    float* out = (float*)d_out;

    hipLaunchKernelGGL(zero_ws_kernel, dim3(1), dim3(64), 0, stream,
                       (unsigned int*)d_ws);
    dim3 grid(W / TILE, H / TILE, B);
    hipLaunchKernelGGL(curvature_main, grid, dim3(NTHREADS), 0, stream,
                       pred, s_ws, c_ws);
    hipLaunchKernelGGL(finalize_kernel, dim3(1), dim3(64), 0, stream,
                       s_ws, c_ws, out);
}

// Round 3
// 74.996 us; speedup vs baseline: 2.2893x; 2.0591x over previous
//
#include <hip/hip_runtime.h>

// CurvatureLoss: pred (8,4,1024,1024) fp32 -> scalar loss. target unused.
// Wave-autonomous sweep: no barriers, no LDS staging; rolling register
// stencil with __shfl for horizontal neighbors.

namespace {
constexpr int H = 1024, W = 1024, B = 8;
constexpr int VALID = 58;                         // valid output cols per wave
constexpr int NSTRIPS = (W + VALID - 1) / VALID;  // 18
constexpr int RCHUNK = 32;                        // output rows per wave
constexpr int NCHUNKS = H / RCHUNK;               // 32
constexpr int WPB = 4;                            // waves per block
constexpr int NTHREADS = 64 * WPB;
}

// ws layout: float s[24] | unsigned c[24]  (8 batches x 3 fields)
__global__ void zero_ws_kernel(unsigned int* ws) {
    if (threadIdx.x < 48) ws[threadIdx.x] = 0u;
}

__device__ __forceinline__ void load_row(const float* __restrict__ base, int row,
                                         float x[4]) {
    const int rc = min(max(row, 0), H - 1);   // clamped addr; value masked later
    const size_t off = (size_t)rc * W;
    x[0] = base[off];
    x[1] = base[off + (size_t)H * W];
    x[2] = base[off + 2 * (size_t)H * W];
    x[3] = base[off + 3 * (size_t)H * W];
}

__device__ __forceinline__ void softmax3(const float x[4], bool ok, float p[3]) {
    const float m = fmaxf(fmaxf(x[0], x[1]), fmaxf(x[2], x[3]));
    const float e0 = __expf(x[0] - m), e1 = __expf(x[1] - m);
    const float e2 = __expf(x[2] - m), e3 = __expf(x[3] - m);
    const float inv = __builtin_amdgcn_rcpf(e0 + e1 + e2 + e3);
    p[0] = ok ? e1 * inv : 0.f;
    p[1] = ok ? (e1 + e2) * inv : 0.f;
    p[2] = ok ? e3 * inv : 0.f;
}

__global__ __launch_bounds__(NTHREADS, 4)
void curvature_sweep(const float* __restrict__ pred,
                     float* __restrict__ s_ws,
                     unsigned int* __restrict__ c_ws) {
    __shared__ float redS[3][WPB];
    __shared__ unsigned int redC[3][WPB];

    const int b = blockIdx.z;
    const int strip = blockIdx.x;
    const int tid = threadIdx.x;
    const int wv = tid >> 6, lane = tid & 63;
    const int r0 = (blockIdx.y * WPB + wv) * RCHUNK;

    const int col = strip * VALID - 3 + lane;
    const bool colOK = (unsigned)col < (unsigned)W;
    const int colC = min(max(col, 0), W - 1);
    const float* base = pred + (size_t)b * 4 * H * W + colC;

    const bool accOK = (lane >= 3) && (lane <= 60) && colOK;
    const float gxpM = (col + 1 < W) ? 1.f : 0.f;   // right-edge pad mask
    const float gxmM = (col >= 1) ? 1.f : 0.f;      // left-edge pad mask

    float pA[3], pB[3], pC[3];
    float l0[3], l1[3], l2[3], l3[3], l4[3];
    float raw[4], nxt[4];
    float sacc[3] = {0.f, 0.f, 0.f};
    unsigned int cacc[3] = {0u, 0u, 0u};
#pragma unroll
    for (int f = 0; f < 3; ++f) { l0[f] = l1[f] = l2[f] = l3[f] = l4[f] = 0.f; }

    // Pre-seed: pA = p[r0-3], pB = p[r0-2], raw = channels of row r0-1.
    load_row(base, r0 - 3, raw);
    softmax3(raw, colOK && (unsigned)(r0 - 3) < (unsigned)H, pA);
    load_row(base, r0 - 2, raw);
    softmax3(raw, colOK && (unsigned)(r0 - 2) < (unsigned)H, pB);
    load_row(base, r0 - 1, raw);

    // 4 prologue steps (fill lap ring) + RCHUNK output steps.
    for (int y = r0 - 4; y < r0 + RCHUNK; ++y) {
        // raw holds channels of row y+3 -> pC = prob row y+3.
        softmax3(raw, colOK && (unsigned)(y + 3) < (unsigned)H, pC);
        load_row(base, y + 4, nxt);   // prefetch next row (latency hidden)

        const bool lapOK = (unsigned)(y + 2) < (unsigned)H;
#pragma unroll
        for (int f = 0; f < 3; ++f) {
            const float left  = __shfl(pB[f], lane - 1, 64);
            const float right = __shfl(pB[f], lane + 1, 64);
            float lp = pA[f] + pC[f] + left + right - 4.f * pB[f];
            lp = (lapOK && colOK) ? lp : 0.f;
            l0[f] = l1[f]; l1[f] = l2[f]; l2[f] = l3[f]; l3[f] = l4[f]; l4[f] = lp;
        }

        if (y >= r0) {   // wave-uniform branch
            const float gypM = (y + 1 < H) ? 1.f : 0.f;
            const float gymM = (y >= 1) ? 1.f : 0.f;
#pragma unroll
            for (int f = 0; f < 3; ++f) {
                const float c   = l2[f];                       // lap(y, x)
                const float cp1 = __shfl(l2[f], lane + 1, 64); // lap(y, x+1)
                const float cm1 = __shfl(l2[f], lane - 1, 64);
                const float cp2 = __shfl(l2[f], lane + 2, 64);
                const float cm2 = __shfl(l2[f], lane - 2, 64);
                const float gx  = cp1 - cm1;
                const float gy  = l3[f] - l1[f];
                const float gxp = (cp2 - c) * gxpM;
                const float gxm = (c - cm2) * gxmM;
                const float gyp = (l4[f] - c) * gypM;
                const float gym = (c - l0[f]) * gymM;
                const float hxx = 2.f * gx - gxp - gxm;
                const float hxy = gxp - gxm;
                const float hyy = 2.f * gy - gyp - gym;
                const float oy = 1.f + gy, ox = 1.f + gx;
                const float numer = hxx * oy * oy - 2.f * hxy * gx * gy
                                  + hyy * ox * ox;
                const float xx = 1.f + gx * gx + gy * gy;
                const float rs = __builtin_amdgcn_rsqf(xx);
                const float inv_den = 0.5f * rs * rs * rs;     // 1/(2 xx^1.5)
                const float curv = numer * inv_den;
                const float negc = fmaxf(-curv, 0.f);
                sacc[f] += accOK ? negc : 0.f;
                cacc[f] += (accOK && negc != 0.f) ? 1u : 0u;
            }
        }

#pragma unroll
        for (int f = 0; f < 3; ++f) { pA[f] = pB[f]; pB[f] = pC[f]; }
#pragma unroll
        for (int k = 0; k < 4; ++k) raw[k] = nxt[k];
    }

    // Wave reduction, then cross-wave via tiny LDS, then one atomic per field.
#pragma unroll
    for (int f = 0; f < 3; ++f) {
        float v = sacc[f];
        unsigned int c = cacc[f];
        for (int off = 32; off > 0; off >>= 1) {
            v += __shfl_xor(v, off, 64);
            c += __shfl_xor(c, off, 64);
        }
        if (lane == 0) { redS[f][wv] = v; redC[f][wv] = c; }
    }
    __syncthreads();
    if (tid < 3) {
        float v = 0.f;
        unsigned int c = 0;
        for (int w2 = 0; w2 < WPB; ++w2) { v += redS[tid][w2]; c += redC[tid][w2]; }
        atomicAdd(&s_ws[b * 3 + tid], v);
        atomicAdd(&c_ws[b * 3 + tid], c);
    }
}

__global__ void finalize_kernel(const float* __restrict__ s_ws,
                                const unsigned int* __restrict__ c_ws,
                                float* __restrict__ out) {
    const int lane = threadIdx.x;
    float v = 0.f;
    if (lane < 24) {
        const float s = s_ws[lane];
        const unsigned int c = c_ws[lane];
        v = (c > 0) ? s / (float)c : 0.f;  // max(c,1)==c when c>0
    }
    for (int off = 32; off > 0; off >>= 1) v += __shfl_down(v, off, 64);
    if (lane == 0) out[0] = v;
}

extern "C" void kernel_launch(void* const* d_in, const int* in_sizes, int n_in,
                              void* d_out, int out_size, void* d_ws, size_t ws_size,
                              hipStream_t stream) {
    const float* pred = (const float*)d_in[0];
    float* s_ws = (float*)d_ws;
    unsigned int* c_ws = (unsigned int*)((char*)d_ws + 24 * sizeof(float));
    float* out = (float*)d_out;

    hipLaunchKernelGGL(zero_ws_kernel, dim3(1), dim3(64), 0, stream,
                       (unsigned int*)d_ws);
    dim3 grid(NSTRIPS, NCHUNKS / WPB, B);
    hipLaunchKernelGGL(curvature_sweep, grid, dim3(NTHREADS), 0, stream,
                       pred, s_ws, c_ws);
    hipLaunchKernelGGL(finalize_kernel, dim3(1), dim3(64), 0, stream,
                       s_ws, c_ws, out);
}